// Round 7
// baseline (490.968 us; speedup 1.0000x reference)
//
#include <hip/hip_runtime.h>
#include <hip/hip_bf16.h>
#include <cstdint>
#include <cstddef>

// Problem constants (from reference): N=50000, E=800000, IN=512, HID=256, MID=128, OUT=64
#define F_IN  512
#define F_HID 256
#define F_MID 128
#define F_OUT 64

typedef __attribute__((ext_vector_type(8))) short short8;   // 8 x bf16 (4 VGPRs)
typedef __attribute__((ext_vector_type(4))) float floatx4;  // MFMA accumulator

static __device__ __forceinline__ float b2f(ushort u) {
  union { unsigned u; float f; } v; v.u = ((unsigned)u) << 16; return v.f;
}
static __device__ __forceinline__ ushort f2b(float f) {
  union { float f; unsigned u; } v; v.f = f;
  unsigned r = v.u + 0x7fffu + ((v.u >> 16) & 1u);  // round-to-nearest-even
  return (ushort)(r >> 16);
}
// 8x f32 -> 8x bf16 via packed v_cvt_pk_bf16_f32 (RNE)
static __device__ __forceinline__ short8 cvt8(float4 lo, float4 hi) {
  union { __hip_bfloat162 h[4]; short8 s; } r;
  r.h[0] = __float22bfloat162_rn({lo.x, lo.y});
  r.h[1] = __float22bfloat162_rn({lo.z, lo.w});
  r.h[2] = __float22bfloat162_rn({hi.x, hi.y});
  r.h[3] = __float22bfloat162_rn({hi.z, hi.w});
  return r.s;
}

// ---------------- CSR build ----------------

__global__ __launch_bounds__(256) void hist_kernel(const int* __restrict__ dst,
                                                   int* __restrict__ cnt, int e) {
  int i = blockIdx.x * 256 + threadIdx.x;
  if (i < e) atomicAdd(&cnt[dst[i]], 1);
}

__global__ __launch_bounds__(256) void dinv_kernel(const int* __restrict__ cnt,
                                                   float* __restrict__ dinv, int n) {
  int i = blockIdx.x * 256 + threadIdx.x;
  if (i < n) dinv[i] = rsqrtf(1.0f + (float)cnt[i]);  // deg includes self-loop
}

// hierarchical scan: (1) per-block exclusive scan + partial; zeroes cnt for cursor reuse
__global__ __launch_bounds__(1024) void scan1_kernel(int* __restrict__ cnt,
                                                     int* __restrict__ rp,
                                                     int* __restrict__ part, int n) {
  __shared__ int buf[1024];
  int tid = threadIdx.x;
  int i = blockIdx.x * 1024 + tid;
  int v = (i < n) ? cnt[i] : 0;
  buf[tid] = v;
  __syncthreads();
  for (int off = 1; off < 1024; off <<= 1) {
    int t = (tid >= off) ? buf[tid - off] : 0;
    __syncthreads();
    buf[tid] += t;
    __syncthreads();
  }
  if (i < n) { rp[i] = buf[tid] - v; cnt[i] = 0; }
  if (tid == 1023) part[blockIdx.x] = buf[1023];
}

// (2) scan of block partials (nb <= 1024), also writes rp[n] = total (== E)
__global__ __launch_bounds__(1024) void scan2_kernel(int* __restrict__ part,
                                                     int* __restrict__ rp, int nb, int n) {
  __shared__ int buf[1024];
  int tid = threadIdx.x;
  int v = (tid < nb) ? part[tid] : 0;
  buf[tid] = v;
  __syncthreads();
  for (int off = 1; off < 1024; off <<= 1) {
    int t = (tid >= off) ? buf[tid - off] : 0;
    __syncthreads();
    buf[tid] += t;
    __syncthreads();
  }
  if (tid < nb) part[tid] = buf[tid] - v;   // exclusive block offsets
  if (tid == nb - 1) rp[n] = buf[tid];      // total
}

// (3) add block offsets
__global__ __launch_bounds__(1024) void scan3_kernel(const int* __restrict__ part,
                                                     int* __restrict__ rp, int n) {
  int b = blockIdx.x;
  int i = b * 1024 + threadIdx.x;
  if (b > 0 && i < n) rp[i] += part[b];
}

__global__ __launch_bounds__(256) void fill_kernel(const int* __restrict__ src,
                                                   const int* __restrict__ dst,
                                                   const int* __restrict__ rp,
                                                   int* __restrict__ cur,
                                                   int* __restrict__ srcs, int e) {
  int i = blockIdx.x * 256 + threadIdx.x;
  if (i < e) {
    int d = dst[i];
    int p = rp[d] + atomicAdd(&cur[d], 1);
    srcs[p] = src[i];
  }
}

// W (f32, [K][F]) -> WT (bf16, [F][K])
__global__ __launch_bounds__(256) void transpose_kernel(const float* __restrict__ W,
                                                        ushort* __restrict__ WT,
                                                        int K, int F) {
  int i = blockIdx.x * 256 + threadIdx.x;
  if (i < K * F) {
    int k = i / F, f = i - k * F;
    WT[(size_t)f * K + k] = f2b(W[i]);
  }
}

// ---------------- B-resident MFMA GEMM: C[M,F] = A[M,K] * B[K,F], BT bf16 [F][K] ----------------
// Thin-GEMM, barrier-free K loop. The WHOLE B panel (NT=64 cols x full K, <=64 KB) is staged
// into LDS ONCE, pre-arranged in MFMA-fragment order: frag (j,c) = 64 lanes x 16B contiguous
// -> conflict-free ds_read_b128; staging writes are thread-consecutive 16B -> conflict-free.
// ONE __syncthreads() total. Then each wave free-runs: raw A chunks prefetched distance-1
// from global into VGPRs (bf16 conversion deferred to use so the vmcnt wait lands after the
// previous chunk's MFMAs), MFMA against LDS-resident B. No barrier in the loop => the
// compiler's fine-grained vmcnt/lgkmcnt scheduling applies; rounds 3-6 proved any K-loop
// containing __syncthreads (= s_waitcnt vmcnt(0) drain) plateaus at 70-95us for this shape.
// Block = 4 waves x 32 rows = 128 rows. Grid: x = column panel (fast axis, so blocks sharing
// A rows are co-resident and A is HBM-fetched once), y = row tile. OOB rows index-clamped.
template<int K, int NT, bool A_F32, bool OUT_F32>
__global__ __launch_bounds__(256, 2) void gemm_bres(const void* __restrict__ Av,
                                                    const ushort* __restrict__ BT,
                                                    const float* __restrict__ bias,
                                                    void* __restrict__ Cv,
                                                    int M, int F) {
  constexpr int NJ = NT / 16;         // 4 col-frag tiles
  constexpr int KC = K / 32;          // k-chunks (16/8/4)
  __shared__ ushort Bs[NT * K];       // 64/32/16 KB
  const int tid = threadIdx.x, lane = tid & 63, wv = tid >> 6;
  const int q = lane >> 4, ml = lane & 15;
  const int bn = blockIdx.x * NT;     // panel (fast grid axis)
  const int bm = blockIdx.y << 7;     // 128 rows per block

  // ---- stage whole B panel in fragment order (one-time) ----
#pragma unroll
  for (int i = 0; i < (NJ * KC * 64) / 256; i++) {
    int ch = i * 256 + tid;
    int j = ch / (KC * 64);
    int c = (ch >> 6) % KC;
    int l = ch & 63;
    int row = bn + j * 16 + (l & 15);       // output col (always < F: NT divides F)
    int col = c * 32 + (l >> 4) * 8;        // k offset
    *(uint4*)(Bs + (size_t)ch * 8) = *(const uint4*)(BT + (size_t)row * K + col);
  }
  __syncthreads();   // the ONLY barrier

  const int rbase = bm + wv * 32;
  const int r0 = min(rbase + ml, M - 1);
  const int r1 = min(rbase + 16 + ml, M - 1);

  floatx4 acc0[NJ] = {}, acc1[NJ] = {};

  // raw A fetch (no conversion -> waitcnt sits at use, not at fetch)
  uint4 ra[4], rn[4];
  auto fetch = [&](int c, uint4* r) {
    const int kk = c * 32 + q * 8;
    if (A_F32) {
      const float* A = (const float*)Av;
      r[0] = *(const uint4*)(A + (size_t)r0 * K + kk);
      r[1] = *(const uint4*)(A + (size_t)r0 * K + kk + 4);
      r[2] = *(const uint4*)(A + (size_t)r1 * K + kk);
      r[3] = *(const uint4*)(A + (size_t)r1 * K + kk + 4);
    } else {
      const ushort* A = (const ushort*)Av;
      r[0] = *(const uint4*)(A + (size_t)r0 * K + kk);
      r[1] = *(const uint4*)(A + (size_t)r1 * K + kk);
    }
  };
  auto toFrag = [&](const uint4* r, short8& a0, short8& a1) {
    if (A_F32) {
      union { uint4 u; float4 f; } c0, c1, c2, c3;
      c0.u = r[0]; c1.u = r[1]; c2.u = r[2]; c3.u = r[3];
      a0 = cvt8(c0.f, c1.f); a1 = cvt8(c2.f, c3.f);
    } else {
      union { uint4 u; short8 s; } c0, c1;
      c0.u = r[0]; c1.u = r[1];
      a0 = c0.s; a1 = c1.s;
    }
  };

  fetch(0, ra);
#pragma unroll
  for (int c = 0; c < KC; c++) {
    if (c + 1 < KC) fetch(c + 1, rn);
    short8 a0, a1;
    toFrag(ra, a0, a1);
#pragma unroll
    for (int j = 0; j < NJ; j++) {
      short8 b = *(const short8*)(Bs + ((size_t)(j * KC + c) * 64 + lane) * 8);
      acc0[j] = __builtin_amdgcn_mfma_f32_16x16x32_bf16(a0, b, acc0[j], 0, 0, 0);
      acc1[j] = __builtin_amdgcn_mfma_f32_16x16x32_bf16(a1, b, acc1[j], 0, 0, 0);
    }
#pragma unroll
    for (int t = 0; t < 4; t++) ra[t] = rn[t];
  }

  // ---- epilogue: C/D col = lane&15, row = quad*4 + reg [m89 verified] ----
#pragma unroll
  for (int j = 0; j < NJ; j++) {
    int n = bn + j * 16 + ml;
    float bv = bias ? bias[n] : 0.0f;
#pragma unroll
    for (int rr = 0; rr < 4; rr++) {
      int m0 = rbase + q * 4 + rr;
      int m1 = rbase + 16 + q * 4 + rr;
      if (m0 < M) {
        float val = acc0[j][rr] + bv;
        if (OUT_F32) ((float*)Cv)[(size_t)m0 * F + n] = val;
        else         ((ushort*)Cv)[(size_t)m0 * F + n] = f2b(val);
      }
      if (m1 < M) {
        float val = acc1[j][rr] + bv;
        if (OUT_F32) ((float*)Cv)[(size_t)m1 * F + n] = val;
        else         ((ushort*)Cv)[(size_t)m1 * F + n] = f2b(val);
      }
    }
  }
}

// ---------------- GCN aggregation: out[d] = relu(b + dinv_d^2*H[d] + sum_e dinv_s*dinv_d*H[s]) ----------------
// one wave per destination node; lane holds F/64 contiguous features. H bf16, out bf16, bias f32.
// Edge loop unrolled x8: ~17 outstanding VMEM ops/wave for latency hiding.
template<int F>
__global__ __launch_bounds__(256) void agg_kernel(const ushort* __restrict__ H,
                                                  const float* __restrict__ bias,
                                                  const float* __restrict__ dinv,
                                                  const int* __restrict__ rp,
                                                  const int* __restrict__ srcs,
                                                  ushort* __restrict__ out, int n) {
  constexpr int VPL = F / 64;
  int wid = blockIdx.x * 4 + (threadIdx.x >> 6);
  if (wid >= n) return;
  int lane = threadIdx.x & 63;
  int fo = lane * VPL;
  const ushort* Hf = H + fo;
  float invd = dinv[wid];
  float acc[VPL];
#pragma unroll
  for (int v = 0; v < VPL; v++) acc[v] = bias[fo + v];
  {
    float ws = invd * invd;
    if (VPL == 4) {
      ushort4 hv = *(const ushort4*)(Hf + (size_t)wid * F);
      acc[0] += ws * b2f(hv.x); acc[1] += ws * b2f(hv.y);
      acc[2] += ws * b2f(hv.z); acc[3] += ws * b2f(hv.w);
    } else {
      ushort2 hv = *(const ushort2*)(Hf + (size_t)wid * F);
      acc[0] += ws * b2f(hv.x); acc[1] += ws * b2f(hv.y);
    }
  }
  int p = rp[wid], p1 = rp[wid + 1];
  for (; p + 8 <= p1; p += 8) {
    int s[8];
#pragma unroll
    for (int u = 0; u < 8; u++) s[u] = srcs[p + u];
    float w[8];
#pragma unroll
    for (int u = 0; u < 8; u++) w[u] = dinv[s[u]] * invd;
    if (VPL == 4) {
      ushort4 h[8];
#pragma unroll
      for (int u = 0; u < 8; u++) h[u] = *(const ushort4*)(Hf + (size_t)s[u] * F);
#pragma unroll
      for (int u = 0; u < 8; u++) {
        acc[0] += w[u] * b2f(h[u].x); acc[1] += w[u] * b2f(h[u].y);
        acc[2] += w[u] * b2f(h[u].z); acc[3] += w[u] * b2f(h[u].w);
      }
    } else {
      ushort2 h[8];
#pragma unroll
      for (int u = 0; u < 8; u++) h[u] = *(const ushort2*)(Hf + (size_t)s[u] * F);
#pragma unroll
      for (int u = 0; u < 8; u++) {
        acc[0] += w[u] * b2f(h[u].x); acc[1] += w[u] * b2f(h[u].y);
      }
    }
  }
  for (; p < p1; ++p) {
    int s = srcs[p];
    float w = dinv[s] * invd;
    if (VPL == 4) {
      ushort4 hv = *(const ushort4*)(Hf + (size_t)s * F);
      acc[0] += w * b2f(hv.x); acc[1] += w * b2f(hv.y);
      acc[2] += w * b2f(hv.z); acc[3] += w * b2f(hv.w);
    } else {
      ushort2 hv = *(const ushort2*)(Hf + (size_t)s * F);
      acc[0] += w * b2f(hv.x); acc[1] += w * b2f(hv.y);
    }
  }
  ushort* op = out + (size_t)wid * F + fo;
#pragma unroll
  for (int v = 0; v < VPL; v++) op[v] = f2b(fmaxf(acc[v], 0.0f));
}

// ---------------- log_softmax over 64 classes: one wave per row, f32 in/out ----------------
__global__ __launch_bounds__(256) void logsoftmax_kernel(const float* __restrict__ logits,
                                                         float* __restrict__ out, int n) {
  int wid = blockIdx.x * 4 + (threadIdx.x >> 6);
  if (wid >= n) return;
  int lane = threadIdx.x & 63;
  float l = logits[(size_t)wid * 64 + lane];
  float m = l;
#pragma unroll
  for (int off = 32; off; off >>= 1) m = fmaxf(m, __shfl_xor(m, off, 64));
  float e = __expf(l - m);
#pragma unroll
  for (int off = 32; off; off >>= 1) e += __shfl_xor(e, off, 64);
  out[(size_t)wid * 64 + lane] = (l - m) - __logf(e);
}

// ---------------- launch ----------------

extern "C" void kernel_launch(void* const* d_in, const int* in_sizes, int n_in,
                              void* d_out, int out_size, void* d_ws, size_t ws_size,
                              hipStream_t stream) {
  const float* x  = (const float*)d_in[0];   // f32 per reference dtypes
  const int* ei   = (const int*)d_in[1];
  const float* W1 = (const float*)d_in[2];
  const float* b1 = (const float*)d_in[3];
  const float* W2 = (const float*)d_in[4];
  const float* b2 = (const float*)d_in[5];
  const float* Wc = (const float*)d_in[6];
  const float* bc = (const float*)d_in[7];

  const int N = in_sizes[0] / F_IN;
  const int E = in_sizes[1] / 2;
  const int* e_src = ei;
  const int* e_dst = ei + E;

  // workspace layout (256B aligned slices); total ~55.3 MB
  char* ws = (char*)d_ws;
  size_t off = 0;
  auto alloc = [&](size_t bytes) { char* p = ws + off; off += (bytes + 255) & ~(size_t)255; return p; };
  int*    cnt  = (int*)alloc((size_t)N * 4);
  float*  dinv = (float*)alloc((size_t)N * 4);
  int*    rp   = (int*)alloc((size_t)(N + 1) * 4);
  int*    part = (int*)alloc((size_t)1024 * 4);
  int*    srcs = (int*)alloc((size_t)E * 4);
  ushort* w1t  = (ushort*)alloc((size_t)F_HID * F_IN * 2);
  ushort* w2t  = (ushort*)alloc((size_t)F_MID * F_HID * 2);
  ushort* wct  = (ushort*)alloc((size_t)F_OUT * F_MID * 2);
  ushort* bufH = (ushort*)alloc((size_t)N * F_HID * 2);  // pre-agg H; reused as fp32 logits (N*64*4 == N*256 B <= N*512 B)
  ushort* bufG = (ushort*)alloc((size_t)N * F_HID * 2);  // post-agg h
  (void)ws_size; (void)n_in; (void)out_size;

  int gE = (E + 255) / 256, gW = (N + 3) / 4;
  int gM128 = (N + 127) / 128;
  int nb = (N + 1023) / 1024;

  // CSR + dinv
  hipMemsetAsync(cnt, 0, (size_t)N * 4, stream);
  hist_kernel<<<gE, 256, 0, stream>>>(e_dst, cnt, E);
  dinv_kernel<<<(N + 255) / 256, 256, 0, stream>>>(cnt, dinv, N);
  scan1_kernel<<<nb, 1024, 0, stream>>>(cnt, rp, part, N);
  scan2_kernel<<<1, 1024, 0, stream>>>(part, rp, nb, N);
  scan3_kernel<<<nb, 1024, 0, stream>>>(part, rp, N);
  fill_kernel<<<gE, 256, 0, stream>>>(e_src, e_dst, rp, cnt, srcs, E);

  // weight transposes (f32 -> bf16 B^T layout)
  transpose_kernel<<<(F_IN * F_HID + 255) / 256, 256, 0, stream>>>(W1, w1t, F_IN, F_HID);
  transpose_kernel<<<(F_HID * F_MID + 255) / 256, 256, 0, stream>>>(W2, w2t, F_HID, F_MID);
  transpose_kernel<<<(F_MID * F_OUT + 255) / 256, 256, 0, stream>>>(Wc, wct, F_MID, F_OUT);

  // layer 1: H = x @ W1 (f32 A, barrier-free K loop, 4 col panels x 391 row tiles)
  gemm_bres<512, 64, true, false><<<dim3(F_HID / 64, gM128), 256, 0, stream>>>(x, w1t, nullptr, bufH, N, F_HID);
  agg_kernel<F_HID><<<gW, 256, 0, stream>>>(bufH, b1, dinv, rp, srcs, bufG, N);

  // layer 2: H2 = h1 @ W2 (2 col panels x 391 row tiles)
  gemm_bres<256, 64, false, false><<<dim3(F_MID / 64, gM128), 256, 0, stream>>>(bufG, w2t, nullptr, bufH, N, F_MID);
  agg_kernel<F_MID><<<gW, 256, 0, stream>>>(bufH, b2, dinv, rp, srcs, bufG, N);

  // classifier: logits = h2 @ Wc + bc (1 col panel x 391 row tiles, fp32 into bufH)
  gemm_bres<128, 64, false, true><<<dim3(1, gM128), 256, 0, stream>>>(bufG, wct, bc, (void*)bufH, N, F_OUT);
  logsoftmax_kernel<<<gW, 256, 0, stream>>>((const float*)bufH, (float*)d_out, N);
}

// Round 8
// 430.063 us; speedup vs baseline: 1.1416x; 1.1416x over previous
//
#include <hip/hip_runtime.h>
#include <hip/hip_bf16.h>
#include <cstdint>
#include <cstddef>

// Problem constants (from reference): N=50000, E=800000, IN=512, HID=256, MID=128, OUT=64
#define F_IN  512
#define F_HID 256
#define F_MID 128
#define F_OUT 64

typedef __attribute__((ext_vector_type(8))) short short8;   // 8 x bf16 (4 VGPRs)
typedef __attribute__((ext_vector_type(4))) float floatx4;  // MFMA accumulator

static __device__ __forceinline__ float b2f(ushort u) {
  union { unsigned u; float f; } v; v.u = ((unsigned)u) << 16; return v.f;
}
static __device__ __forceinline__ ushort f2b(float f) {
  union { float f; unsigned u; } v; v.f = f;
  unsigned r = v.u + 0x7fffu + ((v.u >> 16) & 1u);  // round-to-nearest-even
  return (ushort)(r >> 16);
}
// 8x f32 -> 8x bf16 via packed v_cvt_pk_bf16_f32 (RNE)
static __device__ __forceinline__ short8 cvt8(float4 lo, float4 hi) {
  union { __hip_bfloat162 h[4]; short8 s; } r;
  r.h[0] = __float22bfloat162_rn({lo.x, lo.y});
  r.h[1] = __float22bfloat162_rn({lo.z, lo.w});
  r.h[2] = __float22bfloat162_rn({hi.x, hi.y});
  r.h[3] = __float22bfloat162_rn({hi.z, hi.w});
  return r.s;
}

// ---------------- CSR build ----------------

__global__ __launch_bounds__(256) void hist_kernel(const int* __restrict__ dst,
                                                   int* __restrict__ cnt, int e) {
  int i = blockIdx.x * 256 + threadIdx.x;
  if (i < e) atomicAdd(&cnt[dst[i]], 1);
}

__global__ __launch_bounds__(256) void dinv_kernel(const int* __restrict__ cnt,
                                                   float* __restrict__ dinv, int n) {
  int i = blockIdx.x * 256 + threadIdx.x;
  if (i < n) dinv[i] = rsqrtf(1.0f + (float)cnt[i]);  // deg includes self-loop
}

// hierarchical scan: (1) per-block exclusive scan + partial; zeroes cnt for cursor reuse
__global__ __launch_bounds__(1024) void scan1_kernel(int* __restrict__ cnt,
                                                     int* __restrict__ rp,
                                                     int* __restrict__ part, int n) {
  __shared__ int buf[1024];
  int tid = threadIdx.x;
  int i = blockIdx.x * 1024 + tid;
  int v = (i < n) ? cnt[i] : 0;
  buf[tid] = v;
  __syncthreads();
  for (int off = 1; off < 1024; off <<= 1) {
    int t = (tid >= off) ? buf[tid - off] : 0;
    __syncthreads();
    buf[tid] += t;
    __syncthreads();
  }
  if (i < n) { rp[i] = buf[tid] - v; cnt[i] = 0; }
  if (tid == 1023) part[blockIdx.x] = buf[1023];
}

// (2) scan of block partials (nb <= 1024), also writes rp[n] = total (== E)
__global__ __launch_bounds__(1024) void scan2_kernel(int* __restrict__ part,
                                                     int* __restrict__ rp, int nb, int n) {
  __shared__ int buf[1024];
  int tid = threadIdx.x;
  int v = (tid < nb) ? part[tid] : 0;
  buf[tid] = v;
  __syncthreads();
  for (int off = 1; off < 1024; off <<= 1) {
    int t = (tid >= off) ? buf[tid - off] : 0;
    __syncthreads();
    buf[tid] += t;
    __syncthreads();
  }
  if (tid < nb) part[tid] = buf[tid] - v;   // exclusive block offsets
  if (tid == nb - 1) rp[n] = buf[tid];      // total
}

// (3) add block offsets
__global__ __launch_bounds__(1024) void scan3_kernel(const int* __restrict__ part,
                                                     int* __restrict__ rp, int n) {
  int b = blockIdx.x;
  int i = b * 1024 + threadIdx.x;
  if (b > 0 && i < n) rp[i] += part[b];
}

__global__ __launch_bounds__(256) void fill_kernel(const int* __restrict__ src,
                                                   const int* __restrict__ dst,
                                                   const int* __restrict__ rp,
                                                   int* __restrict__ cur,
                                                   int* __restrict__ srcs, int e) {
  int i = blockIdx.x * 256 + threadIdx.x;
  if (i < e) {
    int d = dst[i];
    int p = rp[d] + atomicAdd(&cur[d], 1);
    srcs[p] = src[i];
  }
}

// W (f32, [K][F]) -> WT (bf16, [F][K])
__global__ __launch_bounds__(256) void transpose_kernel(const float* __restrict__ W,
                                                        ushort* __restrict__ WT,
                                                        int K, int F) {
  int i = blockIdx.x * 256 + threadIdx.x;
  if (i < K * F) {
    int k = i / F, f = i - k * F;
    WT[(size_t)f * K + k] = f2b(W[i]);
  }
}

// ---------------- 64-row MFMA GEMM, double-buffered: C[M,F] = A[M,K]*B[K,F], BT bf16 [F][K] ----
// Tile 64(M) x NT(N), BK=32, two LDS buffers, ONE barrier per K-iter. Loads for tile k+1 are
// issued at the top of iter k (raw, unconverted); the vmcnt wait lands at the LDS-write AFTER
// the MFMAs, so load latency overlaps compute within a block and across the ~3 resident
// blocks/CU. Rounds 3-7 showed: 2-barrier loops (vmcnt(0) drain each iter) plateau at 70-95us
// and a fully barrier-free B-resident variant regressed (64KB LDS, depth-1 prefetch).
// Small tile keeps grid large: gemm1 = 1564 blocks = 6.1/CU. LDS 24 KB, K template-unrolled.
// OOB rows index-clamped on loads, guarded on stores.
template<int K, int NT, bool A_F32, bool OUT_F32>
__global__ __launch_bounds__(256) void gemm64db(const void* __restrict__ Av,
                                                const ushort* __restrict__ BT,
                                                const float* __restrict__ bias,
                                                void* __restrict__ Cv,
                                                int M, int F) {
  constexpr int NJ = NT / 64;         // col-tiles per wave (128->2, 64->1)
  constexpr int NAV = A_F32 ? 2 : 1;  // raw A regs per stage (uint4)
  __shared__ ushort As[2][64 * 32];   // 2 x 4 KB
  __shared__ ushort Bs[2][NT * 32];   // 2 x 8 KB (NT=128) / 2 x 4 KB (NT=64)
  const int tid = threadIdx.x, lane = tid & 63, wv = tid >> 6;
  const int q = lane >> 4, ml = lane & 15;
  const int bm = blockIdx.x << 6, bn = blockIdx.y * NT;
  const int wn = wv * (NT / 4);

  const int sr = tid >> 2, sc = (tid & 3) << 3;   // staging: row 0..63, col 0/8/16/24
  const int ra  = min(bm + sr, M - 1);
  const int rb0 = min(bn + sr, F - 1);
  const int rb1 = min(bn + 64 + sr, F - 1);       // only used when NT==128

  uint4 avr[NAV], bvr0, bvr1;                     // raw staged regs (current)
  uint4 nvr[NAV], nvb0, nvb1;                     // raw staged regs (next)

  auto fetch = [&](int k0, uint4* av, uint4& b0, uint4& b1) {
    if (A_F32) {
      const float* A = (const float*)Av;
      av[0] = *(const uint4*)(A + (size_t)ra * K + k0 + sc);
      av[1] = *(const uint4*)(A + (size_t)ra * K + k0 + sc + 4);
    } else {
      av[0] = *(const uint4*)((const ushort*)Av + (size_t)ra * K + k0 + sc);
    }
    b0 = *(const uint4*)(BT + (size_t)rb0 * K + k0 + sc);
    if (NT == 128) b1 = *(const uint4*)(BT + (size_t)rb1 * K + k0 + sc);
  };
  auto stage = [&](int buf, const uint4* av, const uint4& b0, const uint4& b1) {
    if (A_F32) {
      union { uint4 u[2]; float4 f[2]; } c; c.u[0] = av[0]; c.u[1] = av[1];
      union { short8 s; uint4 u; } o; o.s = cvt8(c.f[0], c.f[1]);
      *(uint4*)(As[buf] + sr * 32 + sc) = o.u;
    } else {
      *(uint4*)(As[buf] + sr * 32 + sc) = av[0];
    }
    *(uint4*)(Bs[buf] + sr * 32 + sc) = b0;
    if (NT == 128) *(uint4*)(Bs[buf] + (64 + sr) * 32 + sc) = b1;
  };

  floatx4 acc[4][NJ] = {};

  // prologue: stage tile 0 into buffer 0
  fetch(0, avr, bvr0, bvr1);
  stage(0, avr, bvr0, bvr1);
  __syncthreads();

#pragma unroll
  for (int k0 = 0; k0 < K; k0 += 32) {
    const int cur = (k0 >> 5) & 1, nxt = cur ^ 1;
    const bool more = (k0 + 32 < K);
    if (more) fetch(k0 + 32, nvr, nvb0, nvb1);   // issue next-tile loads, no wait yet

    short8 af[4], bf[NJ];
#pragma unroll
    for (int i = 0; i < 4; i++)
      af[i] = *(const short8*)(As[cur] + (16 * i + ml) * 32 + q * 8);
#pragma unroll
    for (int j = 0; j < NJ; j++)
      bf[j] = *(const short8*)(Bs[cur] + (wn + 16 * j + ml) * 32 + q * 8);
#pragma unroll
    for (int i = 0; i < 4; i++)
#pragma unroll
      for (int j = 0; j < NJ; j++)
        acc[i][j] = __builtin_amdgcn_mfma_f32_16x16x32_bf16(af[i], bf[j], acc[i][j], 0, 0, 0);

    if (more) {
      stage(nxt, nvr, nvb0, nvb1);   // vmcnt wait lands here, AFTER the MFMAs
      __syncthreads();               // guards buf[nxt] reads (iter k-1) vs this write
    }
  }

  // epilogue: C/D col = lane&15, row = quad*4 + reg [m89 verified]
#pragma unroll
  for (int j = 0; j < NJ; j++) {
    int n = bn + wn + 16 * j + ml;
    float bv = bias ? bias[n] : 0.0f;
#pragma unroll
    for (int i = 0; i < 4; i++) {
#pragma unroll
      for (int rr = 0; rr < 4; rr++) {
        int m = bm + 16 * i + q * 4 + rr;
        if (m < M) {
          float val = acc[i][j][rr] + bv;
          if (OUT_F32) ((float*)Cv)[(size_t)m * F + n] = val;
          else         ((ushort*)Cv)[(size_t)m * F + n] = f2b(val);
        }
      }
    }
  }
}

// ---------------- GCN aggregation: out[d] = relu(b + dinv_d^2*H[d] + sum_e dinv_s*dinv_d*H[s]) ----------------
// one wave per destination node; lane holds F/64 contiguous features. H bf16, out bf16, bias f32.
// Edge loop unrolled x8: ~17 outstanding VMEM ops/wave for latency hiding.
template<int F>
__global__ __launch_bounds__(256) void agg_kernel(const ushort* __restrict__ H,
                                                  const float* __restrict__ bias,
                                                  const float* __restrict__ dinv,
                                                  const int* __restrict__ rp,
                                                  const int* __restrict__ srcs,
                                                  ushort* __restrict__ out, int n) {
  constexpr int VPL = F / 64;
  int wid = blockIdx.x * 4 + (threadIdx.x >> 6);
  if (wid >= n) return;
  int lane = threadIdx.x & 63;
  int fo = lane * VPL;
  const ushort* Hf = H + fo;
  float invd = dinv[wid];
  float acc[VPL];
#pragma unroll
  for (int v = 0; v < VPL; v++) acc[v] = bias[fo + v];
  {
    float ws = invd * invd;
    if (VPL == 4) {
      ushort4 hv = *(const ushort4*)(Hf + (size_t)wid * F);
      acc[0] += ws * b2f(hv.x); acc[1] += ws * b2f(hv.y);
      acc[2] += ws * b2f(hv.z); acc[3] += ws * b2f(hv.w);
    } else {
      ushort2 hv = *(const ushort2*)(Hf + (size_t)wid * F);
      acc[0] += ws * b2f(hv.x); acc[1] += ws * b2f(hv.y);
    }
  }
  int p = rp[wid], p1 = rp[wid + 1];
  for (; p + 8 <= p1; p += 8) {
    int s[8];
#pragma unroll
    for (int u = 0; u < 8; u++) s[u] = srcs[p + u];
    float w[8];
#pragma unroll
    for (int u = 0; u < 8; u++) w[u] = dinv[s[u]] * invd;
    if (VPL == 4) {
      ushort4 h[8];
#pragma unroll
      for (int u = 0; u < 8; u++) h[u] = *(const ushort4*)(Hf + (size_t)s[u] * F);
#pragma unroll
      for (int u = 0; u < 8; u++) {
        acc[0] += w[u] * b2f(h[u].x); acc[1] += w[u] * b2f(h[u].y);
        acc[2] += w[u] * b2f(h[u].z); acc[3] += w[u] * b2f(h[u].w);
      }
    } else {
      ushort2 h[8];
#pragma unroll
      for (int u = 0; u < 8; u++) h[u] = *(const ushort2*)(Hf + (size_t)s[u] * F);
#pragma unroll
      for (int u = 0; u < 8; u++) {
        acc[0] += w[u] * b2f(h[u].x); acc[1] += w[u] * b2f(h[u].y);
      }
    }
  }
  for (; p < p1; ++p) {
    int s = srcs[p];
    float w = dinv[s] * invd;
    if (VPL == 4) {
      ushort4 hv = *(const ushort4*)(Hf + (size_t)s * F);
      acc[0] += w * b2f(hv.x); acc[1] += w * b2f(hv.y);
      acc[2] += w * b2f(hv.z); acc[3] += w * b2f(hv.w);
    } else {
      ushort2 hv = *(const ushort2*)(Hf + (size_t)s * F);
      acc[0] += w * b2f(hv.x); acc[1] += w * b2f(hv.y);
    }
  }
  ushort* op = out + (size_t)wid * F + fo;
#pragma unroll
  for (int v = 0; v < VPL; v++) op[v] = f2b(fmaxf(acc[v], 0.0f));
}

// ---------------- log_softmax over 64 classes: one wave per row, f32 in/out ----------------
__global__ __launch_bounds__(256) void logsoftmax_kernel(const float* __restrict__ logits,
                                                         float* __restrict__ out, int n) {
  int wid = blockIdx.x * 4 + (threadIdx.x >> 6);
  if (wid >= n) return;
  int lane = threadIdx.x & 63;
  float l = logits[(size_t)wid * 64 + lane];
  float m = l;
#pragma unroll
  for (int off = 32; off; off >>= 1) m = fmaxf(m, __shfl_xor(m, off, 64));
  float e = __expf(l - m);
#pragma unroll
  for (int off = 32; off; off >>= 1) e += __shfl_xor(e, off, 64);
  out[(size_t)wid * 64 + lane] = (l - m) - __logf(e);
}

// ---------------- launch ----------------

extern "C" void kernel_launch(void* const* d_in, const int* in_sizes, int n_in,
                              void* d_out, int out_size, void* d_ws, size_t ws_size,
                              hipStream_t stream) {
  const float* x  = (const float*)d_in[0];   // f32 per reference dtypes
  const int* ei   = (const int*)d_in[1];
  const float* W1 = (const float*)d_in[2];
  const float* b1 = (const float*)d_in[3];
  const float* W2 = (const float*)d_in[4];
  const float* b2 = (const float*)d_in[5];
  const float* Wc = (const float*)d_in[6];
  const float* bc = (const float*)d_in[7];

  const int N = in_sizes[0] / F_IN;
  const int E = in_sizes[1] / 2;
  const int* e_src = ei;
  const int* e_dst = ei + E;

  // workspace layout (256B aligned slices); total ~55.3 MB
  char* ws = (char*)d_ws;
  size_t off = 0;
  auto alloc = [&](size_t bytes) { char* p = ws + off; off += (bytes + 255) & ~(size_t)255; return p; };
  int*    cnt  = (int*)alloc((size_t)N * 4);
  float*  dinv = (float*)alloc((size_t)N * 4);
  int*    rp   = (int*)alloc((size_t)(N + 1) * 4);
  int*    part = (int*)alloc((size_t)1024 * 4);
  int*    srcs = (int*)alloc((size_t)E * 4);
  ushort* w1t  = (ushort*)alloc((size_t)F_HID * F_IN * 2);
  ushort* w2t  = (ushort*)alloc((size_t)F_MID * F_HID * 2);
  ushort* wct  = (ushort*)alloc((size_t)F_OUT * F_MID * 2);
  ushort* bufH = (ushort*)alloc((size_t)N * F_HID * 2);  // pre-agg H; reused as fp32 logits (N*64*4 == N*256 B <= N*512 B)
  ushort* bufG = (ushort*)alloc((size_t)N * F_HID * 2);  // post-agg h
  (void)ws_size; (void)n_in; (void)out_size;

  int gE = (E + 255) / 256, gW = (N + 3) / 4;
  int gM64 = (N + 63) / 64;
  int nb = (N + 1023) / 1024;

  // CSR + dinv
  hipMemsetAsync(cnt, 0, (size_t)N * 4, stream);
  hist_kernel<<<gE, 256, 0, stream>>>(e_dst, cnt, E);
  dinv_kernel<<<(N + 255) / 256, 256, 0, stream>>>(cnt, dinv, N);
  scan1_kernel<<<nb, 1024, 0, stream>>>(cnt, rp, part, N);
  scan2_kernel<<<1, 1024, 0, stream>>>(part, rp, nb, N);
  scan3_kernel<<<nb, 1024, 0, stream>>>(part, rp, N);
  fill_kernel<<<gE, 256, 0, stream>>>(e_src, e_dst, rp, cnt, srcs, E);

  // weight transposes (f32 -> bf16 B^T layout)
  transpose_kernel<<<(F_IN * F_HID + 255) / 256, 256, 0, stream>>>(W1, w1t, F_IN, F_HID);
  transpose_kernel<<<(F_HID * F_MID + 255) / 256, 256, 0, stream>>>(W2, w2t, F_HID, F_MID);
  transpose_kernel<<<(F_MID * F_OUT + 255) / 256, 256, 0, stream>>>(Wc, wct, F_MID, F_OUT);

  // layer 1: H = x @ W1 (f32 A, 64x128 tiles, double-buffered, 1564 blocks)
  gemm64db<512, 128, true, false><<<dim3(gM64, F_HID / 128), 256, 0, stream>>>(x, w1t, nullptr, bufH, N, F_HID);
  agg_kernel<F_HID><<<gW, 256, 0, stream>>>(bufH, b1, dinv, rp, srcs, bufG, N);

  // layer 2: H2 = h1 @ W2 (64x128 tiles, 782 blocks)
  gemm64db<256, 128, false, false><<<dim3(gM64, 1), 256, 0, stream>>>(bufG, w2t, nullptr, bufH, N, F_MID);
  agg_kernel<F_MID><<<gW, 256, 0, stream>>>(bufH, b2, dinv, rp, srcs, bufG, N);

  // classifier: logits = h2 @ Wc + bc (64x64 tiles, fp32 into bufH), then log_softmax -> d_out (f32)
  gemm64db<128, 64, false, true><<<dim3(gM64, 1), 256, 0, stream>>>(bufG, wct, bc, (void*)bufH, N, F_OUT);
  logsoftmax_kernel<<<gW, 256, 0, stream>>>((const float*)bufH, (float*)d_out, N);
}